// Round 8
// baseline (432.324 us; speedup 1.0000x reference)
//
#include <hip/hip_runtime.h>
#include <hip/hip_bf16.h>

typedef float f32x2 __attribute__((ext_vector_type(2)));
typedef unsigned int u32;
typedef u32 u32x4 __attribute__((ext_vector_type(4)));

// ---------------------------------------------------------------------------
// Mixed-layout bf16 tables in ws (ushort offsets), total 1,830,912 ushorts
// = 3.66 MB  (< 4 MiB per-XCD L2):
//   EXPANDED (64B entries [y][x][4 corners][8ch]) for small levels:
//     sp0 @ 0        (3*16*16*32  = 24576)
//     sp1 @ 24576    (3*32*32*32  = 98304)
//     sp2 @ 122880   (3*64*64*32  = 393216)
//     tp0 @ 516096   (3*16*100*32 = 153600)
//     tp1 @ 669696   (3*32*100*32 = 307200)
//   PLAIN (16B entries [y][x][8ch]) for big levels:
//     sp3 @ 976896   (3*128*128*8 = 393216)
//     tp2 @ 1370112  (3*64*100*8  = 153600)
//     tp3 @ 1523712  (3*128*100*8 = 307200)
// ---------------------------------------------------------------------------
#define EXP_SP0 0
#define EXP_SP1 24576
#define EXP_SP2 122880
#define EXP_TP0 516096
#define EXP_TP1 669696
#define PL_SP3  976896
#define PL_TP2  1370112
#define PL_TP3  1523712

// Build all tables; blockIdx.y = table id:
// 0..2 = sp0..sp2 expanded, 3..4 = tp0..tp1 expanded, 5 = sp3, 6 = tp2, 7 = tp3
__global__ __launch_bounds__(256) void build_tabs(
    const float* __restrict__ sp0, const float* __restrict__ sp1,
    const float* __restrict__ sp2, const float* __restrict__ sp3,
    const float* __restrict__ tp0, const float* __restrict__ tp1,
    const float* __restrict__ tp2, const float* __restrict__ tp3,
    unsigned short* __restrict__ dst)
{
    int tab = blockIdx.y;
    const float* src; int W, H, off; bool ex;
    switch (tab) {
        case 0: src = sp0; W = 16;  H = 16;  off = EXP_SP0; ex = true;  break;
        case 1: src = sp1; W = 32;  H = 32;  off = EXP_SP1; ex = true;  break;
        case 2: src = sp2; W = 64;  H = 64;  off = EXP_SP2; ex = true;  break;
        case 3: src = tp0; W = 100; H = 16;  off = EXP_TP0; ex = true;  break;
        case 4: src = tp1; W = 100; H = 32;  off = EXP_TP1; ex = true;  break;
        case 5: src = sp3; W = 128; H = 128; off = PL_SP3;  ex = false; break;
        case 6: src = tp2; W = 100; H = 64;  off = PL_TP2;  ex = false; break;
        default:src = tp3; W = 100; H = 128; off = PL_TP3;  ex = false; break;
    }
    int HW = W * H;
    int per = ex ? 32 : 8;
    int total = 3 * HW * per;
    int i = blockIdx.x * 256 + threadIdx.x;
    if (i >= total) return;

    int c = i & 7;
    int k = ex ? ((i >> 3) & 3) : 0;
    int q = i / per;            // pl*HW + y*W + x
    int x  = q % W;
    int y  = (q / W) % H;
    int pl = q / HW;
    int xk = min(x + (k & 1), W - 1);
    int yk = min(y + (k >> 1), H - 1);
    float v = src[(size_t)(pl * 8 + c) * HW + (size_t)yk * W + xk];
    __hip_bfloat16 b = __float2bfloat16(v);   // round-to-nearest
    dst[off + i] = *reinterpret_cast<unsigned short*>(&b);
}

__device__ __forceinline__ float dpp_add2(float x) {
    // quad butterfly sum: all 4 lanes of each quad end with the quad total
    x += __int_as_float(__builtin_amdgcn_mov_dpp(__float_as_int(x), 0xB1, 0xF, 0xF, true));
    x += __int_as_float(__builtin_amdgcn_mov_dpp(__float_as_int(x), 0x4E, 0xF, 0xF, true));
    return x;
}

// ---------------------------------------------------------------------------
// Main kernel: block = 384 = 4 points x 24 samples x 4 corners.
// tid = p*96 + s*4 + k; quad = one sample. Expanded levels: quad's 4 lanes
// load one 64B entry (1 line/quad). Plain levels: lane k loads corner k's
// 16B entry (~2.3 lines/quad). DPP quad-reduce; lane k stores ch {2k,2k+1}
// -> out + 2*gtid (perfectly linear nontemporal full lines).
// ---------------------------------------------------------------------------
__global__ __launch_bounds__(384) void hexplane_mix(
    const float* __restrict__ xyz, const float* __restrict__ t,
    const float* __restrict__ bounds, const unsigned short* __restrict__ tw,
    float* __restrict__ out, int N)
{
    __shared__ float coords[4][4];   // normalized xn,yn,zn,t per point

    int tid = threadIdx.x;
    int n0  = blockIdx.x * 4;

    if (tid < 16) {
        int p = tid >> 2, comp = tid & 3;
        int n = n0 + p;
        float v = 0.0f;
        if (n < N) {
            if (comp < 3) {
                float b0 = bounds[comp], b1 = bounds[3 + comp];
                v = (xyz[(size_t)n * 3 + comp] - b0) / (b1 - b0);
            } else {
                v = t[n];
            }
        }
        coords[p][comp] = v;
    }
    __syncthreads();

    int p   = tid / 96;
    int rem = tid - p * 96;
    int s   = rem >> 2;
    int k   = rem & 3;
    int g   = s >> 2;
    int r   = s & 3;
    int res = 16 << r;
    int n   = n0 + p;

    float xn = coords[p][0], yn = coords[p][1], zn = coords[p][2], tt = coords[p][3];

    int W, H;
    float ix, iy;
    bool ex;
    int base;
    if (g < 3) {
        W = res; H = res;
        ex = (r < 3);
        if (ex) {
            int lo = (r==0) ? EXP_SP0 : (r==1) ? EXP_SP1 : EXP_SP2;
            base = lo + g * res * res * 32;
        } else {
            base = PL_SP3 + g * 128 * 128 * 8;
        }
        float fx = (g==2) ? yn : xn;
        float fy = (g==0) ? yn : zn;
        ix = fx * (float)W - 0.5f;       // align_corners = False
        iy = fy * (float)H - 0.5f;
    } else {
        int q = g - 3;
        W = 100; H = res;
        ex = (r < 2);
        if (ex) {
            int lo = (r==0) ? EXP_TP0 : EXP_TP1;
            base = lo + q * res * 100 * 32;
        } else {
            int lo = (r==2) ? PL_TP2 : PL_TP3;
            base = lo + q * res * 100 * 8;
        }
        float fy = (q==0) ? xn : (q==1) ? yn : zn;
        ix = tt * 99.0f;                 // align_corners = True, W=100
        iy = fy * (float)(H - 1);
    }

    ix = fminf(fmaxf(ix, 0.0f), (float)(W - 1));
    iy = fminf(fmaxf(iy, 0.0f), (float)(H - 1));
    float x0f = floorf(ix), y0f = floorf(iy);
    float wx = ix - x0f, wy = iy - y0f;
    int x0 = (int)x0f, y0 = (int)y0f;

    float wk = ((k & 1) ? wx : 1.0f - wx) * ((k & 2) ? wy : 1.0f - wy);

    const unsigned short* addr;
    if (ex) {
        addr = tw + base + (size_t)(y0 * W + x0) * 32 + k * 8;
    } else {
        int xk = min(x0 + (k & 1), W - 1);
        int yk = min(y0 + ((k >> 1) & 1), H - 1);
        addr = tw + base + (size_t)(yk * W + xk) * 8;
    }
    u32x4 cv = *(const u32x4*)addr;

    float p0 = __uint_as_float(cv[0] << 16)         * wk;
    float p1 = __uint_as_float(cv[0] & 0xffff0000u) * wk;
    float p2 = __uint_as_float(cv[1] << 16)         * wk;
    float p3 = __uint_as_float(cv[1] & 0xffff0000u) * wk;
    float p4 = __uint_as_float(cv[2] << 16)         * wk;
    float p5 = __uint_as_float(cv[2] & 0xffff0000u) * wk;
    float p6 = __uint_as_float(cv[3] << 16)         * wk;
    float p7 = __uint_as_float(cv[3] & 0xffff0000u) * wk;

    p0 = dpp_add2(p0); p1 = dpp_add2(p1);
    p2 = dpp_add2(p2); p3 = dpp_add2(p3);
    p4 = dpp_add2(p4); p5 = dpp_add2(p5);
    p6 = dpp_add2(p6); p7 = dpp_add2(p7);

    // lane k stores channels {2k, 2k+1}
    float a0 = (k & 1) ? p2 : p0,  a1 = (k & 1) ? p3 : p1;
    float b0 = (k & 1) ? p6 : p4,  b1 = (k & 1) ? p7 : p5;
    f32x2 o;
    o[0] = (k & 2) ? b0 : a0;
    o[1] = (k & 2) ? b1 : a1;

    if (n < N) {
        size_t gidx = (size_t)blockIdx.x * 384 + tid;
        __builtin_nontemporal_store(o, (f32x2*)(out + 2 * gidx));
    }
}

extern "C" void kernel_launch(void* const* d_in, const int* in_sizes, int n_in,
                              void* d_out, int out_size, void* d_ws, size_t ws_size,
                              hipStream_t stream) {
    // setup_inputs() dict order is INTERLEAVED: xyz, t, bounds,
    // sp0, tp0, sp1, tp1, sp2, tp2, sp3, tp3
    const float* xyz    = (const float*)d_in[0];
    const float* t      = (const float*)d_in[1];
    const float* bounds = (const float*)d_in[2];
    const float* sp[4]  = { (const float*)d_in[3], (const float*)d_in[5],
                            (const float*)d_in[7], (const float*)d_in[9] };
    const float* tp[4]  = { (const float*)d_in[4], (const float*)d_in[6],
                            (const float*)d_in[8], (const float*)d_in[10] };
    float* out = (float*)d_out;

    int N = in_sizes[0] / 3;
    unsigned short* tw = (unsigned short*)d_ws;

    // largest table segment: 393216 ushorts -> 1536 blocks of 256
    build_tabs<<<dim3(1536, 8), 256, 0, stream>>>(
        sp[0], sp[1], sp[2], sp[3], tp[0], tp[1], tp[2], tp[3], tw);

    int blocks = (N + 3) / 4;   // 4 points per 384-thread block
    hexplane_mix<<<blocks, 384, 0, stream>>>(xyz, t, bounds, tw, out, N);
}

// Round 9
// 242.461 us; speedup vs baseline: 1.7831x; 1.7831x over previous
//
#include <hip/hip_runtime.h>
#include <hip/hip_bf16.h>

typedef float f32x2 __attribute__((ext_vector_type(2)));
typedef float f32x4 __attribute__((ext_vector_type(4)));
typedef unsigned int u32;
typedef u32 u32x4 __attribute__((ext_vector_type(4)));

// ---------------------------------------------------------------------------
// Mixed-layout bf16 tables in ws (ushort offsets), total 1,830,912 ushorts
// = 3.66 MB (< 4 MiB per-XCD L2):
//  EXPANDED dot2 layout (64B entries) for small levels:
//    per (pl,y,x): dwords 0..7  = top pairs (v(y,x,c), v(y,x1,c))  c=0..7
//                  dwords 8..15 = bot pairs (v(y1,x,c), v(y1,x1,c))
//    (x1,y1 pre-clamped)
//    sp0 @ 0        sp1 @ 24576   sp2 @ 122880   tp0 @ 516096   tp1 @ 669696
//  PLAIN (16B entries [y][x][8ch]) for big levels:
//    sp3 @ 976896   tp2 @ 1370112  tp3 @ 1523712
// ---------------------------------------------------------------------------
#define EXP_SP0 0
#define EXP_SP1 24576
#define EXP_SP2 122880
#define EXP_TP0 516096
#define EXP_TP1 669696
#define PL_SP3  976896
#define PL_TP2  1370112
#define PL_TP3  1523712

__global__ __launch_bounds__(256) void build_tabs(
    const float* __restrict__ sp0, const float* __restrict__ sp1,
    const float* __restrict__ sp2, const float* __restrict__ sp3,
    const float* __restrict__ tp0, const float* __restrict__ tp1,
    const float* __restrict__ tp2, const float* __restrict__ tp3,
    unsigned short* __restrict__ dst)
{
    int tab = blockIdx.y;
    const float* src; int W, H, off; bool ex;
    switch (tab) {
        case 0: src = sp0; W = 16;  H = 16;  off = EXP_SP0; ex = true;  break;
        case 1: src = sp1; W = 32;  H = 32;  off = EXP_SP1; ex = true;  break;
        case 2: src = sp2; W = 64;  H = 64;  off = EXP_SP2; ex = true;  break;
        case 3: src = tp0; W = 100; H = 16;  off = EXP_TP0; ex = true;  break;
        case 4: src = tp1; W = 100; H = 32;  off = EXP_TP1; ex = true;  break;
        case 5: src = sp3; W = 128; H = 128; off = PL_SP3;  ex = false; break;
        case 6: src = tp2; W = 100; H = 64;  off = PL_TP2;  ex = false; break;
        default:src = tp3; W = 100; H = 128; off = PL_TP3;  ex = false; break;
    }
    int HW = W * H;
    int per = ex ? 32 : 8;
    int total = 3 * HW * per;
    int i = blockIdx.x * 256 + threadIdx.x;
    if (i >= total) return;

    int q = i / per;            // pl*HW + y*W + x
    int x  = q % W;
    int y  = (q / W) % H;
    int pl = q / HW;

    int c, xk, yk;
    if (ex) {
        int u = i & 31, d = u >> 1, half = u & 1;
        c  = d & 7;
        xk = min(x + half, W - 1);
        yk = (d >> 3) ? min(y + 1, H - 1) : y;
    } else {
        c = i & 7; xk = x; yk = y;
    }
    float v = src[(size_t)(pl * 8 + c) * HW + (size_t)yk * W + xk];
    __hip_bfloat16 b = __float2bfloat16(v);   // round-to-nearest
    dst[off + i] = *reinterpret_cast<unsigned short*>(&b);
}

__device__ __forceinline__ float dot2bf(u32 ab, u32 w, float acc) {
    float d;
    asm("v_dot2_f32_bf16 %0, %1, %2, %3" : "=v"(d) : "v"(ab), "v"(w), "v"(acc));
    return d;
}
__device__ __forceinline__ u32 pk_bf16(float lo, float hi) {
    u32 d;
    asm("v_cvt_pk_bf16_f32 %0, %1, %2" : "=v"(d) : "v"(lo), "v"(hi));
    return d;
}

// ---------------------------------------------------------------------------
// Main kernel: 192 threads = 8 points x 24 samples. tid = p*24 + s.
// Expanded levels: 4x dwordx4 from ONE 64B entry, 16 dot2.
// Plain levels: 4 corner dwordx4 + 16 v_perm + 16 dot2.
// Output via swizzled LDS bounce -> perfectly linear NT f32x4 stores.
// ---------------------------------------------------------------------------
__global__ __launch_bounds__(192) void hexplane_dot2(
    const float* __restrict__ xyz, const float* __restrict__ t,
    const float* __restrict__ bounds, const unsigned short* __restrict__ tw,
    float* __restrict__ out, int N)
{
    __shared__ float coords[8][4];      // normalized xn,yn,zn,t
    __shared__ float ostage[1536];      // 6 KB bounce

    int tid = threadIdx.x;
    int n0  = blockIdx.x * 8;

    if (tid < 32) {
        int p = tid >> 2, comp = tid & 3;
        int n = n0 + p;
        float v = 0.0f;
        if (n < N) {
            if (comp < 3) {
                float b0 = bounds[comp], b1 = bounds[3 + comp];
                v = (xyz[(size_t)n * 3 + comp] - b0) / (b1 - b0);
            } else {
                v = t[n];
            }
        }
        coords[p][comp] = v;
    }
    __syncthreads();

    int p = tid / 24;
    int s = tid - p * 24;
    int g = s >> 2;
    int r = s & 3;
    int res = 16 << r;

    f32x4 cd = *(f32x4*)&coords[p][0];
    float xn = cd[0], yn = cd[1], zn = cd[2], tt = cd[3];

    int W, H;
    float ix, iy;
    bool ex;
    int base;
    if (g < 3) {
        W = res; H = res;
        ex = (r < 3);
        if (ex) {
            int lo = (r==0) ? EXP_SP0 : (r==1) ? EXP_SP1 : EXP_SP2;
            base = lo + g * res * res * 32;
        } else {
            base = PL_SP3 + g * 128 * 128 * 8;
        }
        float fx = (g==2) ? yn : xn;
        float fy = (g==0) ? yn : zn;
        ix = fx * (float)W - 0.5f;       // align_corners = False
        iy = fy * (float)H - 0.5f;
    } else {
        int q = g - 3;
        W = 100; H = res;
        ex = (r < 2);
        if (ex) {
            int lo = (r==0) ? EXP_TP0 : EXP_TP1;
            base = lo + q * res * 100 * 32;
        } else {
            int lo = (r==2) ? PL_TP2 : PL_TP3;
            base = lo + q * res * 100 * 8;
        }
        float fy = (q==0) ? xn : (q==1) ? yn : zn;
        ix = tt * 99.0f;                 // align_corners = True, W=100
        iy = fy * (float)(H - 1);
    }

    ix = fminf(fmaxf(ix, 0.0f), (float)(W - 1));
    iy = fminf(fmaxf(iy, 0.0f), (float)(H - 1));
    float x0f = floorf(ix), y0f = floorf(iy);
    float wx = ix - x0f, wy = iy - y0f;
    int x0 = (int)x0f, y0 = (int)y0f;

    float omx = 1.0f - wx, omy = 1.0f - wy;
    u32 wT = pk_bf16(omx * omy, wx * omy);   // (w00, w01)
    u32 wB = pk_bf16(omx * wy,  wx * wy);    // (w10, w11)

    u32 top[8], bot[8];
    if (ex) {
        const u32x4* ep = (const u32x4*)(tw + base + (size_t)(y0 * W + x0) * 32);
        u32x4 t0 = ep[0], t1 = ep[1], b0 = ep[2], b1 = ep[3];
        #pragma unroll
        for (int k = 0; k < 4; ++k) { top[k] = t0[k]; top[4+k] = t1[k]; }
        #pragma unroll
        for (int k = 0; k < 4; ++k) { bot[k] = b0[k]; bot[4+k] = b1[k]; }
    } else {
        int x1 = min(x0 + 1, W - 1), y1 = min(y0 + 1, H - 1);
        const unsigned short* tb = tw + base;
        u32x4 c00 = *(const u32x4*)(tb + (size_t)(y0*W + x0) * 8);
        u32x4 c01 = *(const u32x4*)(tb + (size_t)(y0*W + x1) * 8);
        u32x4 c10 = *(const u32x4*)(tb + (size_t)(y1*W + x0) * 8);
        u32x4 c11 = *(const u32x4*)(tb + (size_t)(y1*W + x1) * 8);
        #pragma unroll
        for (int k = 0; k < 4; ++k) {
            top[2*k]   = __builtin_amdgcn_perm(c00[k], c01[k], 0x01000504u);
            top[2*k+1] = __builtin_amdgcn_perm(c00[k], c01[k], 0x03020706u);
            bot[2*k]   = __builtin_amdgcn_perm(c10[k], c11[k], 0x01000504u);
            bot[2*k+1] = __builtin_amdgcn_perm(c10[k], c11[k], 0x03020706u);
        }
    }

    // interpolate: f[c] = dot2(top[c], wT) + dot2(bot[c], wB)
    // expanded layout: top[c] pairs are already per-channel c=0..7
    // plain layout: perm produced them in channel order too
    float f[8];
    #pragma unroll
    for (int c = 0; c < 8; ++c) {
        float a = dot2bf(top[c], wT, 0.0f);
        f[c] = dot2bf(bot[c], wB, a);
    }

    // bounce write: entry e = tid; pair j at slot j ^ ((e>>2)&3)
    {
        int q = (tid >> 2) & 3;
        #pragma unroll
        for (int j = 0; j < 4; ++j) {
            f32x2 w2 = { f[2*j], f[2*j+1] };
            *(f32x2*)&ostage[tid * 8 + (j ^ q) * 2] = w2;
        }
    }
    __syncthreads();

    // readout: thread u covers flat floats [4u,4u+4) and [768+4u, 768+4u+4)
    size_t total_out = (size_t)N * 192;
    int a = tid & 1;

    int e0 = tid >> 1;
    int q0 = (e0 >> 2) & 3;
    int sg0 = a ^ (q0 >> 1);
    f32x4 v0 = *(f32x4*)&ostage[e0 * 8 + sg0 * 4];
    if (q0 & 1) { f32x4 tmp = { v0[2], v0[3], v0[0], v0[1] }; v0 = tmp; }

    int e1 = 96 + (tid >> 1);
    int q1 = (e1 >> 2) & 3;
    int sg1 = a ^ (q1 >> 1);
    f32x4 v1 = *(f32x4*)&ostage[e1 * 8 + sg1 * 4];
    if (q1 & 1) { f32x4 tmp = { v1[2], v1[3], v1[0], v1[1] }; v1 = tmp; }

    size_t F0 = (size_t)n0 * 192 + (size_t)tid * 4;
    size_t F1 = F0 + 768;
    if (F0 + 4 <= total_out)
        __builtin_nontemporal_store(v0, (f32x4*)(out + F0));
    if (F1 + 4 <= total_out)
        __builtin_nontemporal_store(v1, (f32x4*)(out + F1));
}

extern "C" void kernel_launch(void* const* d_in, const int* in_sizes, int n_in,
                              void* d_out, int out_size, void* d_ws, size_t ws_size,
                              hipStream_t stream) {
    // setup_inputs() dict order is INTERLEAVED: xyz, t, bounds,
    // sp0, tp0, sp1, tp1, sp2, tp2, sp3, tp3
    const float* xyz    = (const float*)d_in[0];
    const float* t      = (const float*)d_in[1];
    const float* bounds = (const float*)d_in[2];
    const float* sp[4]  = { (const float*)d_in[3], (const float*)d_in[5],
                            (const float*)d_in[7], (const float*)d_in[9] };
    const float* tp[4]  = { (const float*)d_in[4], (const float*)d_in[6],
                            (const float*)d_in[8], (const float*)d_in[10] };
    float* out = (float*)d_out;

    int N = in_sizes[0] / 3;
    unsigned short* tw = (unsigned short*)d_ws;

    // largest table segment: 393,216 ushorts -> 1536 blocks of 256
    build_tabs<<<dim3(1536, 8), 256, 0, stream>>>(
        sp[0], sp[1], sp[2], sp[3], tp[0], tp[1], tp[2], tp[3], tw);

    int blocks = (N + 7) / 8;   // 8 points per 192-thread block
    hexplane_dot2<<<blocks, 192, 0, stream>>>(xyz, t, bounds, tw, out, N);
}